// Round 1
// baseline (670.476 us; speedup 1.0000x reference)
//
#include <hip/hip_runtime.h>
#include <hip/hip_bf16.h>
#include <stdint.h>

// TernaryConv2d: y = conv2d(x, alpha*ternary(W), SAME) + b
// x: (32,56,56,256) NHWC fp32, W: (3,3,256,256) HWIO fp32, b: (256,) fp32
// Implicit GEMM: M=100352, N=256, K=2304. bf16 MFMA (ternary weights exact in
// bf16; alpha applied fp32 in epilogue).
//
// ws layout (needs ~57.5 MB):
//   [0..511]            : ull scalars {sumAbs_q40, sumBeyond_q40, countBeyond}
//   [512..2360319]      : WqT bf16 [256 co][2304 k]   (B^T for contiguous frags)
//   [2360320..57467903] : xpad bf16 [32][58][58][256] (zero-padded halo)

typedef __attribute__((ext_vector_type(8))) short short8;
typedef __attribute__((ext_vector_type(4))) float floatx4;

#define Q40 1099511627776.0
#define INV_Q40 (1.0 / 1099511627776.0)
#define NW_ELEMS 589824        // 3*3*256*256
#define K_TOTAL 2304
#define WQT_OFF 512
#define XPAD_OFF 2360320

__device__ __forceinline__ void async16(const void* g, void* l) {
  __builtin_amdgcn_global_load_lds(
      (const __attribute__((address_space(1))) void*)g,
      (__attribute__((address_space(3))) void*)l, 16, 0, 0);
}

__device__ __forceinline__ ushort f2bf(float f) {
  __hip_bfloat16 h = __float2bfloat16(f);
  return *reinterpret_cast<ushort*>(&h);
}

// ---- pad & convert: x fp32 (32,56,56,256) -> xpad bf16 (32,58,58,256) ----
__global__ __launch_bounds__(256) void pad_kernel(const float* __restrict__ x,
                                                  ushort* __restrict__ xpad) {
  uint idx = blockIdx.x * 256 + threadIdx.x;   // one thread per 8 channels
  uint c8 = idx & 31;                          // 8-channel group, 0..31
  uint sp = idx >> 5;                          // n*3364 + hh*58 + ww
  uint ww = sp % 58;
  uint t = sp / 58;
  uint hh = t % 58;
  uint n = t / 58;
  ushort* dst = xpad + ((size_t)sp * 256 + c8 * 8);
  if (hh == 0 || hh == 57 || ww == 0 || ww == 57) {
    uint4 z = {0, 0, 0, 0};
    *(uint4*)dst = z;
  } else {
    const float* src = x + (((size_t)(n * 56 + (hh - 1)) * 56 + (ww - 1)) * 256 + c8 * 8);
    float4 f0 = *(const float4*)src;
    float4 f1 = *(const float4*)(src + 4);
    ushort u[8];
    u[0] = f2bf(f0.x); u[1] = f2bf(f0.y); u[2] = f2bf(f0.z); u[3] = f2bf(f0.w);
    u[4] = f2bf(f1.x); u[5] = f2bf(f1.y); u[6] = f2bf(f1.z); u[7] = f2bf(f1.w);
    *(uint4*)dst = *(uint4*)u;
  }
}

// ---- sum |W| (fixed-point q40 atomics: deterministic, ~fp64 accuracy) ----
__global__ __launch_bounds__(256) void sumabs_kernel(const float* __restrict__ W,
                                                     unsigned long long* __restrict__ scal) {
  uint i = blockIdx.x * 256 + threadIdx.x;
  double v = (double)fabsf(W[i]);
#pragma unroll
  for (int off = 32; off; off >>= 1) v += __shfl_down(v, off);
  if ((threadIdx.x & 63) == 0) {
    atomicAdd(&scal[0], (unsigned long long)(v * Q40 + 0.5));
  }
}

// ---- ternarize: write WqT[co][k] bf16 in {-1,0,+1}; accumulate alpha stats ----
__global__ __launch_bounds__(256) void quant_kernel(const float* __restrict__ W,
                                                    ushort* __restrict__ WqT,
                                                    unsigned long long* __restrict__ scal) {
  double s = (double)scal[0] * INV_Q40;
  float t = (float)(0.7 * (s / (double)NW_ELEMS));
  uint i = blockIdx.x * 256 + threadIdx.x;
  float w = W[i];
  bool pos = (w > t), neg = (w < -t);
  ushort q = pos ? (ushort)0x3F80 : (neg ? (ushort)0xBF80 : (ushort)0);
  uint k = i >> 8, co = i & 255;
  WqT[(size_t)co * K_TOTAL + k] = q;
  bool beyond = pos || neg;
  double v = beyond ? (double)fabsf(w) : 0.0;
#pragma unroll
  for (int off = 32; off; off >>= 1) v += __shfl_down(v, off);
  unsigned long long cnt = __popcll(__ballot(beyond));
  if ((threadIdx.x & 63) == 0) {
    atomicAdd(&scal[1], (unsigned long long)(v * Q40 + 0.5));
    atomicAdd(&scal[2], cnt);
  }
}

// ---- implicit-GEMM conv: 128x128 tile, BK=64, 16x16x32 bf16 MFMA ----
__global__ __launch_bounds__(256, 2) void conv_kernel(
    const ushort* __restrict__ xpad, const ushort* __restrict__ WqT,
    const unsigned long long* __restrict__ scal, const float* __restrict__ bias,
    float* __restrict__ out) {
  __shared__ __attribute__((aligned(16))) ushort Alds[128 * 64];  // [m][k] 16 KB
  __shared__ __attribute__((aligned(16))) ushort Blds[128 * 64];  // [n][k] 16 KB
  uint tid = threadIdx.x;
  uint bm = blockIdx.x >> 1, bn = blockIdx.x & 1;

  // staging source base pointers (tap (0,0), kc=0); 4 issues x 16B per thread
  uint chunk = tid & 7;        // 16B chunk within a 64-elem (128B) row
  uint rbase = tid >> 3;       // 0..31
  const ushort* asrc[4];
  const ushort* bsrc[4];
#pragma unroll
  for (int i = 0; i < 4; i++) {
    uint row = i * 32 + rbase;
    uint gm = bm * 128 + row;
    uint n = gm / 3136;
    uint rem = gm - n * 3136;
    uint h = rem / 56;
    uint w = rem - h * 56;
    // padded coords: input row = h-1+ky -> padded index h+ky (pad=1)
    asrc[i] = xpad + (((size_t)(n * 58 + h) * 58 + w) * 256 + chunk * 8);
    bsrc[i] = WqT + ((size_t)(bn * 128 + row) * K_TOTAL + chunk * 8);
  }

  floatx4 acc[4][4];
#pragma unroll
  for (int mt = 0; mt < 4; mt++)
#pragma unroll
    for (int nt = 0; nt < 4; nt++) acc[mt][nt] = (floatx4){0.f, 0.f, 0.f, 0.f};

  uint lane = tid & 63;
  uint wv = tid >> 6;
  uint wm = wv >> 1, wn = wv & 1;   // 2x2 wave grid, each 64x64
  uint fr = lane & 15, fq = lane >> 4;
  uint a_off = (wm * 64 + fr) * 128 + fq * 16;  // + mt*2048 + kk*64 (bytes)
  uint b_off = (wn * 64 + fr) * 128 + fq * 16;  // + nt*2048 + kk*64

  for (int ks = 0; ks < 36; ks++) {
    uint tap = (uint)ks >> 2;
    uint kc = ((uint)ks & 3) * 64;
    uint ky = tap / 3;
    uint kx = tap - ky * 3;
    uint aoffe = (ky * 58 + kx) * 256 + kc;  // element offset into xpad
    uint boffe = (uint)ks * 64;              // element offset along WqT rows

    __syncthreads();  // previous tile fully consumed
#pragma unroll
    for (int i = 0; i < 4; i++)
      async16(asrc[i] + aoffe, (char*)Alds + i * 4096 + tid * 16);
#pragma unroll
    for (int i = 0; i < 4; i++)
      async16(bsrc[i] + boffe, (char*)Blds + i * 4096 + tid * 16);
    __syncthreads();  // drains vmcnt -> staging complete

#pragma unroll
    for (int kk = 0; kk < 2; kk++) {
      short8 af[4], bfr[4];
#pragma unroll
      for (int mt = 0; mt < 4; mt++)
        af[mt] = *(const short8*)((const char*)Alds + a_off + mt * 2048 + kk * 64);
#pragma unroll
      for (int nt = 0; nt < 4; nt++)
        bfr[nt] = *(const short8*)((const char*)Blds + b_off + nt * 2048 + kk * 64);
#pragma unroll
      for (int mt = 0; mt < 4; mt++)
#pragma unroll
        for (int nt = 0; nt < 4; nt++)
          acc[mt][nt] = __builtin_amdgcn_mfma_f32_16x16x32_bf16(
              af[mt], bfr[nt], acc[mt][nt], 0, 0, 0);
    }
  }

  // epilogue: alpha * acc + bias, fp32 store
  double sb = (double)scal[1] * INV_Q40;
  double cb = (double)scal[2];
  float alpha = (float)(sb / cb);
  // C/D layout (verified m89/m91): col = lane&15, row = (lane>>4)*4 + reg
#pragma unroll
  for (int mt = 0; mt < 4; mt++) {
    uint mb = bm * 128 + wm * 64 + mt * 16 + fq * 4;
#pragma unroll
    for (int r = 0; r < 4; r++) {
      float* orow = out + (size_t)(mb + r) * 256;
#pragma unroll
      for (int nt = 0; nt < 4; nt++) {
        uint n = bn * 128 + wn * 64 + nt * 16 + fr;
        orow[n] = acc[mt][nt][r] * alpha + bias[n];
      }
    }
  }
}

extern "C" void kernel_launch(void* const* d_in, const int* in_sizes, int n_in,
                              void* d_out, int out_size, void* d_ws, size_t ws_size,
                              hipStream_t stream) {
  const float* x = (const float*)d_in[0];
  const float* W = (const float*)d_in[1];
  const float* b = (const float*)d_in[2];
  float* out = (float*)d_out;

  unsigned long long* scal = (unsigned long long*)d_ws;
  ushort* WqT = (ushort*)((char*)d_ws + WQT_OFF);
  ushort* xpad = (ushort*)((char*)d_ws + XPAD_OFF);

  hipMemsetAsync(d_ws, 0, 512, stream);

  // pad+convert: 32*58*58*256/8 = 3,444,224 threads
  pad_kernel<<<13454, 256, 0, stream>>>(x, xpad);
  sumabs_kernel<<<NW_ELEMS / 256, 256, 0, stream>>>(W, scal);
  quant_kernel<<<NW_ELEMS / 256, 256, 0, stream>>>(W, WqT, scal);
  // grid: (M/128) * (N/128) = 784 * 2 = 1568 blocks
  conv_kernel<<<1568, 256, 0, stream>>>(xpad, WqT, scal, b, out);
}

// Round 2
// 349.374 us; speedup vs baseline: 1.9191x; 1.9191x over previous
//
#include <hip/hip_runtime.h>
#include <hip/hip_bf16.h>
#include <stdint.h>

// TernaryConv2d: y = conv2d(x, alpha*ternary(W), SAME) + b
// x: (32,56,56,256) NHWC fp32, W: (3,3,256,256) HWIO fp32, b: (256,) fp32
// Implicit GEMM: M=100352, N=256, K=2304. bf16 MFMA (ternary weights exact in
// bf16; alpha applied fp32 in epilogue).
//
// R1: reductions were 225+110 us of pure same-address atomic serialization
// (1 atomic/wave x 9216 waves). Now: grid-stride 288 blocks, LDS block
// reduction, 1 atomic/block.
//
// ws layout (needs ~57.5 MB):
//   [0..511]            : ull scalars {sumAbs_q40, sumBeyond_q40, countBeyond}
//   [512..2360319]      : WqT bf16 [256 co][2304 k]   (B^T for contiguous frags)
//   [2360320..57467903] : xpad bf16 [32][58][58][256] (zero-padded halo)

typedef __attribute__((ext_vector_type(8))) short short8;
typedef __attribute__((ext_vector_type(4))) float floatx4;

#define Q40 1099511627776.0
#define INV_Q40 (1.0 / 1099511627776.0)
#define NW_ELEMS 589824        // 3*3*256*256
#define K_TOTAL 2304
#define WQT_OFF 512
#define XPAD_OFF 2360320
#define RED_BLOCKS 288         // 288*256*8 == NW_ELEMS exactly

__device__ __forceinline__ void async16(const void* g, void* l) {
  __builtin_amdgcn_global_load_lds(
      (const __attribute__((address_space(1))) void*)g,
      (__attribute__((address_space(3))) void*)l, 16, 0, 0);
}

__device__ __forceinline__ ushort f2bf(float f) {
  __hip_bfloat16 h = __float2bfloat16(f);
  return *reinterpret_cast<ushort*>(&h);
}

// ---- pad & convert: x fp32 (32,56,56,256) -> xpad bf16 (32,58,58,256) ----
__global__ __launch_bounds__(256) void pad_kernel(const float* __restrict__ x,
                                                  ushort* __restrict__ xpad) {
  uint idx = blockIdx.x * 256 + threadIdx.x;   // one thread per 8 channels
  uint c8 = idx & 31;                          // 8-channel group, 0..31
  uint sp = idx >> 5;                          // n*3364 + hh*58 + ww
  uint ww = sp % 58;
  uint t = sp / 58;
  uint hh = t % 58;
  uint n = t / 58;
  ushort* dst = xpad + ((size_t)sp * 256 + c8 * 8);
  if (hh == 0 || hh == 57 || ww == 0 || ww == 57) {
    uint4 z = {0, 0, 0, 0};
    *(uint4*)dst = z;
  } else {
    const float* src = x + (((size_t)(n * 56 + (hh - 1)) * 56 + (ww - 1)) * 256 + c8 * 8);
    float4 f0 = *(const float4*)src;
    float4 f1 = *(const float4*)(src + 4);
    ushort u[8];
    u[0] = f2bf(f0.x); u[1] = f2bf(f0.y); u[2] = f2bf(f0.z); u[3] = f2bf(f0.w);
    u[4] = f2bf(f1.x); u[5] = f2bf(f1.y); u[6] = f2bf(f1.z); u[7] = f2bf(f1.w);
    *(uint4*)dst = *(uint4*)u;
  }
}

// ---- sum |W|: grid-stride, block-reduce, ONE q40 atomic per block ----
__global__ __launch_bounds__(256) void sumabs_kernel(const float* __restrict__ W,
                                                     unsigned long long* __restrict__ scal) {
  __shared__ double sds[4];
  double v = 0.0;
#pragma unroll
  for (int j = 0; j < 8; j++) {
    uint i = (blockIdx.x * 8 + j) * 256 + threadIdx.x;
    v += (double)fabsf(W[i]);
  }
#pragma unroll
  for (int off = 32; off; off >>= 1) v += __shfl_down(v, off);
  if ((threadIdx.x & 63) == 0) sds[threadIdx.x >> 6] = v;
  __syncthreads();
  if (threadIdx.x == 0) {
    double s = sds[0] + sds[1] + sds[2] + sds[3];
    atomicAdd(&scal[0], (unsigned long long)(s * Q40 + 0.5));
  }
}

// ---- ternarize: WqT[co][k] in {-1,0,+1}; alpha stats, 2 atomics/block ----
__global__ __launch_bounds__(256) void quant_kernel(const float* __restrict__ W,
                                                    ushort* __restrict__ WqT,
                                                    unsigned long long* __restrict__ scal) {
  __shared__ double sds[4];
  __shared__ unsigned long long cds[4];
  double s = (double)scal[0] * INV_Q40;
  float t = (float)(0.7 * (s / (double)NW_ELEMS));
  double v = 0.0;
  unsigned long long cnt = 0;
#pragma unroll
  for (int j = 0; j < 8; j++) {
    uint i = (blockIdx.x * 8 + j) * 256 + threadIdx.x;
    float w = W[i];
    bool pos = (w > t), neg = (w < -t);
    ushort q = pos ? (ushort)0x3F80 : (neg ? (ushort)0xBF80 : (ushort)0);
    uint k = i >> 8, co = i & 255;
    WqT[(size_t)co * K_TOTAL + k] = q;
    if (pos || neg) { v += (double)fabsf(w); cnt++; }
  }
#pragma unroll
  for (int off = 32; off; off >>= 1) {
    v += __shfl_down(v, off);
    cnt += __shfl_down(cnt, off);
  }
  if ((threadIdx.x & 63) == 0) { sds[threadIdx.x >> 6] = v; cds[threadIdx.x >> 6] = cnt; }
  __syncthreads();
  if (threadIdx.x == 0) {
    double sv = sds[0] + sds[1] + sds[2] + sds[3];
    unsigned long long sc = cds[0] + cds[1] + cds[2] + cds[3];
    atomicAdd(&scal[1], (unsigned long long)(sv * Q40 + 0.5));
    atomicAdd(&scal[2], sc);
  }
}

// ---- implicit-GEMM conv: 128x128 tile, BK=64, 16x16x32 bf16 MFMA ----
__global__ __launch_bounds__(256, 2) void conv_kernel(
    const ushort* __restrict__ xpad, const ushort* __restrict__ WqT,
    const unsigned long long* __restrict__ scal, const float* __restrict__ bias,
    float* __restrict__ out) {
  __shared__ __attribute__((aligned(16))) ushort Alds[128 * 64];  // [m][k] 16 KB
  __shared__ __attribute__((aligned(16))) ushort Blds[128 * 64];  // [n][k] 16 KB
  uint tid = threadIdx.x;
  uint bm = blockIdx.x >> 1, bn = blockIdx.x & 1;

  // staging source base pointers (tap (0,0), kc=0); 4 issues x 16B per thread
  uint chunk = tid & 7;        // 16B chunk within a 64-elem (128B) row
  uint rbase = tid >> 3;       // 0..31
  const ushort* asrc[4];
  const ushort* bsrc[4];
#pragma unroll
  for (int i = 0; i < 4; i++) {
    uint row = i * 32 + rbase;
    uint gm = bm * 128 + row;
    uint n = gm / 3136;
    uint rem = gm - n * 3136;
    uint h = rem / 56;
    uint w = rem - h * 56;
    // padded coords: input row = h-1+ky -> padded index h+ky (pad=1)
    asrc[i] = xpad + (((size_t)(n * 58 + h) * 58 + w) * 256 + chunk * 8);
    bsrc[i] = WqT + ((size_t)(bn * 128 + row) * K_TOTAL + chunk * 8);
  }

  floatx4 acc[4][4];
#pragma unroll
  for (int mt = 0; mt < 4; mt++)
#pragma unroll
    for (int nt = 0; nt < 4; nt++) acc[mt][nt] = (floatx4){0.f, 0.f, 0.f, 0.f};

  uint lane = tid & 63;
  uint wv = tid >> 6;
  uint wm = wv >> 1, wn = wv & 1;   // 2x2 wave grid, each 64x64
  uint fr = lane & 15, fq = lane >> 4;
  uint a_off = (wm * 64 + fr) * 128 + fq * 16;  // + mt*2048 + kk*64 (bytes)
  uint b_off = (wn * 64 + fr) * 128 + fq * 16;  // + nt*2048 + kk*64

  for (int ks = 0; ks < 36; ks++) {
    uint tap = (uint)ks >> 2;
    uint kc = ((uint)ks & 3) * 64;
    uint ky = tap / 3;
    uint kx = tap - ky * 3;
    uint aoffe = (ky * 58 + kx) * 256 + kc;  // element offset into xpad
    uint boffe = (uint)ks * 64;              // element offset along WqT rows

    __syncthreads();  // previous tile fully consumed
#pragma unroll
    for (int i = 0; i < 4; i++)
      async16(asrc[i] + aoffe, (char*)Alds + i * 4096 + tid * 16);
#pragma unroll
    for (int i = 0; i < 4; i++)
      async16(bsrc[i] + boffe, (char*)Blds + i * 4096 + tid * 16);
    __syncthreads();  // drains vmcnt -> staging complete

#pragma unroll
    for (int kk = 0; kk < 2; kk++) {
      short8 af[4], bfr[4];
#pragma unroll
      for (int mt = 0; mt < 4; mt++)
        af[mt] = *(const short8*)((const char*)Alds + a_off + mt * 2048 + kk * 64);
#pragma unroll
      for (int nt = 0; nt < 4; nt++)
        bfr[nt] = *(const short8*)((const char*)Blds + b_off + nt * 2048 + kk * 64);
#pragma unroll
      for (int mt = 0; mt < 4; mt++)
#pragma unroll
        for (int nt = 0; nt < 4; nt++)
          acc[mt][nt] = __builtin_amdgcn_mfma_f32_16x16x32_bf16(
              af[mt], bfr[nt], acc[mt][nt], 0, 0, 0);
    }
  }

  // epilogue: alpha * acc + bias, fp32 store
  double sb = (double)scal[1] * INV_Q40;
  double cb = (double)scal[2];
  float alpha = (float)(sb / cb);
  // C/D layout (verified m89/m91): col = lane&15, row = (lane>>4)*4 + reg
#pragma unroll
  for (int mt = 0; mt < 4; mt++) {
    uint mb = bm * 128 + wm * 64 + mt * 16 + fq * 4;
#pragma unroll
    for (int r = 0; r < 4; r++) {
      float* orow = out + (size_t)(mb + r) * 256;
#pragma unroll
      for (int nt = 0; nt < 4; nt++) {
        uint n = bn * 128 + wn * 64 + nt * 16 + fr;
        orow[n] = acc[mt][nt][r] * alpha + bias[n];
      }
    }
  }
}

extern "C" void kernel_launch(void* const* d_in, const int* in_sizes, int n_in,
                              void* d_out, int out_size, void* d_ws, size_t ws_size,
                              hipStream_t stream) {
  const float* x = (const float*)d_in[0];
  const float* W = (const float*)d_in[1];
  const float* b = (const float*)d_in[2];
  float* out = (float*)d_out;

  unsigned long long* scal = (unsigned long long*)d_ws;
  ushort* WqT = (ushort*)((char*)d_ws + WQT_OFF);
  ushort* xpad = (ushort*)((char*)d_ws + XPAD_OFF);

  hipMemsetAsync(d_ws, 0, 512, stream);

  // pad+convert: 32*58*58*256/8 = 3,444,224 threads
  pad_kernel<<<13454, 256, 0, stream>>>(x, xpad);
  sumabs_kernel<<<RED_BLOCKS, 256, 0, stream>>>(W, scal);
  quant_kernel<<<RED_BLOCKS, 256, 0, stream>>>(W, WqT, scal);
  // grid: (M/128) * (N/128) = 784 * 2 = 1568 blocks
  conv_kernel<<<1568, 256, 0, stream>>>(xpad, WqT, scal, b, out);
}

// Round 3
// 298.871 us; speedup vs baseline: 2.2434x; 1.1690x over previous
//
#include <hip/hip_runtime.h>
#include <hip/hip_bf16.h>
#include <stdint.h>

// TernaryConv2d: y = conv2d(x, alpha*ternary(W), SAME) + b
// x: (32,56,56,256) NHWC fp32, W: (3,3,256,256) HWIO fp32, b: (256,) fp32
// Implicit GEMM: M=100352, N=256, K=2304. bf16 MFMA, alpha fp32 epilogue.
//
// R1: reduction atomics fixed (670->349).
// R2: (a) XOR-swizzled LDS chunks — rows are 128B (32 banks), unswizzled
//     ds_read_b128 hit banks 0-15 only = 2x penalty, 4.3e7 conflict cycles.
//     (b) kc-outer/tap-inner K-loop — tap re-reads 1 step apart -> L2-hot.
//     (c) sumabs fused into pad (independent inputs).
//
// ws layout:
//   [0..511]            : ull scalars {sumAbs_q40, sumBeyond_q40, countBeyond}
//   [512..2360319]      : WqT bf16 [256 co][2304 k]  (k = tap*256 + ci)
//   [2360320..57467903] : xpad bf16 [32][58][58][256] (zero-padded halo)

typedef __attribute__((ext_vector_type(8))) short short8;
typedef __attribute__((ext_vector_type(4))) float floatx4;

#define Q40 1099511627776.0
#define INV_Q40 (1.0 / 1099511627776.0)
#define NW_ELEMS 589824        // 3*3*256*256
#define K_TOTAL 2304
#define WQT_OFF 512
#define XPAD_OFF 2360320
#define RED_BLOCKS 288         // 288*256*8 == NW_ELEMS exactly
#define PAD_BLOCKS 13454       // 32*58*58*256/8 / 256

__device__ __forceinline__ void async16(const void* g, void* l) {
  __builtin_amdgcn_global_load_lds(
      (const __attribute__((address_space(1))) void*)g,
      (__attribute__((address_space(3))) void*)l, 16, 0, 0);
}

__device__ __forceinline__ ushort f2bf(float f) {
  __hip_bfloat16 h = __float2bfloat16(f);
  return *reinterpret_cast<ushort*>(&h);
}

// ---- fused: blocks 0..287 sum|W|; blocks 288.. pad/convert x -> xpad ----
__global__ __launch_bounds__(256) void pad_sumabs_kernel(
    const float* __restrict__ x, ushort* __restrict__ xpad,
    const float* __restrict__ W, unsigned long long* __restrict__ scal) {
  if (blockIdx.x < RED_BLOCKS) {
    __shared__ double sds[4];
    double v = 0.0;
#pragma unroll
    for (int j = 0; j < 8; j++) {
      uint i = (blockIdx.x * 8 + j) * 256 + threadIdx.x;
      v += (double)fabsf(W[i]);
    }
#pragma unroll
    for (int off = 32; off; off >>= 1) v += __shfl_down(v, off);
    if ((threadIdx.x & 63) == 0) sds[threadIdx.x >> 6] = v;
    __syncthreads();
    if (threadIdx.x == 0) {
      double s = sds[0] + sds[1] + sds[2] + sds[3];
      atomicAdd(&scal[0], (unsigned long long)(s * Q40 + 0.5));
    }
    return;
  }
  uint idx = (blockIdx.x - RED_BLOCKS) * 256 + threadIdx.x;  // 1 thread / 8 ch
  uint c8 = idx & 31;
  uint sp = idx >> 5;                          // n*3364 + hh*58 + ww
  uint ww = sp % 58;
  uint t = sp / 58;
  uint hh = t % 58;
  uint n = t / 58;
  ushort* dst = xpad + ((size_t)sp * 256 + c8 * 8);
  if (hh == 0 || hh == 57 || ww == 0 || ww == 57) {
    uint4 z = {0, 0, 0, 0};
    *(uint4*)dst = z;
  } else {
    const float* src = x + (((size_t)(n * 56 + (hh - 1)) * 56 + (ww - 1)) * 256 + c8 * 8);
    float4 f0 = *(const float4*)src;
    float4 f1 = *(const float4*)(src + 4);
    ushort u[8];
    u[0] = f2bf(f0.x); u[1] = f2bf(f0.y); u[2] = f2bf(f0.z); u[3] = f2bf(f0.w);
    u[4] = f2bf(f1.x); u[5] = f2bf(f1.y); u[6] = f2bf(f1.z); u[7] = f2bf(f1.w);
    *(uint4*)dst = *(uint4*)u;
  }
}

// ---- ternarize: WqT[co][k] in {-1,0,+1}; alpha stats, 2 atomics/block ----
__global__ __launch_bounds__(256) void quant_kernel(const float* __restrict__ W,
                                                    ushort* __restrict__ WqT,
                                                    unsigned long long* __restrict__ scal) {
  __shared__ double sds[4];
  __shared__ unsigned long long cds[4];
  double s = (double)scal[0] * INV_Q40;
  float t = (float)(0.7 * (s / (double)NW_ELEMS));
  double v = 0.0;
  unsigned long long cnt = 0;
#pragma unroll
  for (int j = 0; j < 8; j++) {
    uint i = (blockIdx.x * 8 + j) * 256 + threadIdx.x;
    float w = W[i];
    bool pos = (w > t), neg = (w < -t);
    ushort q = pos ? (ushort)0x3F80 : (neg ? (ushort)0xBF80 : (ushort)0);
    uint k = i >> 8, co = i & 255;
    WqT[(size_t)co * K_TOTAL + k] = q;
    if (pos || neg) { v += (double)fabsf(w); cnt++; }
  }
#pragma unroll
  for (int off = 32; off; off >>= 1) {
    v += __shfl_down(v, off);
    cnt += __shfl_down(cnt, off);
  }
  if ((threadIdx.x & 63) == 0) { sds[threadIdx.x >> 6] = v; cds[threadIdx.x >> 6] = cnt; }
  __syncthreads();
  if (threadIdx.x == 0) {
    double sv = sds[0] + sds[1] + sds[2] + sds[3];
    unsigned long long sc = cds[0] + cds[1] + cds[2] + cds[3];
    atomicAdd(&scal[1], (unsigned long long)(sv * Q40 + 0.5));
    atomicAdd(&scal[2], sc);
  }
}

// ---- implicit-GEMM conv: 128x128 tile, BK=64, 16x16x32 bf16 MFMA ----
// LDS rows: 64 ushort = 128 B = 32 banks. Chunk c of row r stored at chunk
// slot c (staging loads global chunk c^(r&7)), readers fetch slot
// (kk*4+fq)^(fr&7): every bank gets exactly 8 dword accesses per b128 wave
// read -> conflict-free.
__global__ __launch_bounds__(256, 2) void conv_kernel(
    const ushort* __restrict__ xpad, const ushort* __restrict__ WqT,
    const unsigned long long* __restrict__ scal, const float* __restrict__ bias,
    float* __restrict__ out) {
  __shared__ __attribute__((aligned(16))) ushort Alds[128 * 64];  // 16 KB
  __shared__ __attribute__((aligned(16))) ushort Blds[128 * 64];  // 16 KB
  uint tid = threadIdx.x;
  uint bm = blockIdx.x >> 1, bn = blockIdx.x & 1;

  // staging: thread (rbase,chunk) loads global chunk ceff = chunk^(rbase&7)
  uint chunk = tid & 7;
  uint rbase = tid >> 3;       // 0..31
  uint ceff = chunk ^ (rbase & 7);
  const ushort* asrc[4];
  const ushort* bsrc[4];
#pragma unroll
  for (int i = 0; i < 4; i++) {
    uint row = i * 32 + rbase;
    uint gm = bm * 128 + row;
    uint n = gm / 3136;
    uint rem = gm - n * 3136;
    uint h = rem / 56;
    uint w = rem - h * 56;
    asrc[i] = xpad + (((size_t)(n * 58 + h) * 58 + w) * 256 + ceff * 8);
    bsrc[i] = WqT + ((size_t)(bn * 128 + row) * K_TOTAL + ceff * 8);
  }

  floatx4 acc[4][4];
#pragma unroll
  for (int mt = 0; mt < 4; mt++)
#pragma unroll
    for (int nt = 0; nt < 4; nt++) acc[mt][nt] = (floatx4){0.f, 0.f, 0.f, 0.f};

  uint lane = tid & 63;
  uint wv = tid >> 6;
  uint wm = wv >> 1, wn = wv & 1;   // 2x2 wave grid, each 64x64
  uint fr = lane & 15, fq = lane >> 4;
  uint a_row = (wm * 64 + fr) * 128;  // + mt*2048 + swz-chunk*16 (bytes)
  uint b_row = (wn * 64 + fr) * 128;
  uint swz = (fr & 7) * 16;           // XOR byte offset applied to chunk slot

  // K-loop: kc-outer, tap-inner (taps 1 step apart -> A re-reads L2-hot)
  for (int ks = 0; ks < 36; ks++) {
    uint kcq = (uint)ks / 9;
    uint tap = (uint)ks - kcq * 9;
    uint ky = tap / 3;
    uint kx = tap - ky * 3;
    uint aoffe = (ky * 58 + kx) * 256 + kcq * 64;  // elements into xpad
    uint boffe = tap * 256 + kcq * 64;             // elements along WqT row

    __syncthreads();  // previous tile fully consumed
#pragma unroll
    for (int i = 0; i < 4; i++)
      async16(asrc[i] + aoffe, (char*)Alds + i * 4096 + tid * 16);
#pragma unroll
    for (int i = 0; i < 4; i++)
      async16(bsrc[i] + boffe, (char*)Blds + i * 4096 + tid * 16);
    __syncthreads();  // drains vmcnt -> staging complete

#pragma unroll
    for (int kk = 0; kk < 2; kk++) {
      uint csl = ((uint)(kk * 64) + fq * 16) ^ swz;  // swizzled chunk slot
      short8 af[4], bfr[4];
#pragma unroll
      for (int mt = 0; mt < 4; mt++)
        af[mt] = *(const short8*)((const char*)Alds + a_row + mt * 2048 + csl);
#pragma unroll
      for (int nt = 0; nt < 4; nt++)
        bfr[nt] = *(const short8*)((const char*)Blds + b_row + nt * 2048 + csl);
#pragma unroll
      for (int mt = 0; mt < 4; mt++)
#pragma unroll
        for (int nt = 0; nt < 4; nt++)
          acc[mt][nt] = __builtin_amdgcn_mfma_f32_16x16x32_bf16(
              af[mt], bfr[nt], acc[mt][nt], 0, 0, 0);
    }
  }

  // epilogue: alpha * acc + bias, fp32 store
  double sb = (double)scal[1] * INV_Q40;
  double cb = (double)scal[2];
  float alpha = (float)(sb / cb);
  // C/D layout (m89/m91): col = lane&15, row = (lane>>4)*4 + reg
#pragma unroll
  for (int mt = 0; mt < 4; mt++) {
    uint mb = bm * 128 + wm * 64 + mt * 16 + fq * 4;
#pragma unroll
    for (int r = 0; r < 4; r++) {
      float* orow = out + (size_t)(mb + r) * 256;
#pragma unroll
      for (int nt = 0; nt < 4; nt++) {
        uint n = bn * 128 + wn * 64 + nt * 16 + fr;
        orow[n] = acc[mt][nt][r] * alpha + bias[n];
      }
    }
  }
}

extern "C" void kernel_launch(void* const* d_in, const int* in_sizes, int n_in,
                              void* d_out, int out_size, void* d_ws, size_t ws_size,
                              hipStream_t stream) {
  const float* x = (const float*)d_in[0];
  const float* W = (const float*)d_in[1];
  const float* b = (const float*)d_in[2];
  float* out = (float*)d_out;

  unsigned long long* scal = (unsigned long long*)d_ws;
  ushort* WqT = (ushort*)((char*)d_ws + WQT_OFF);
  ushort* xpad = (ushort*)((char*)d_ws + XPAD_OFF);

  hipMemsetAsync(d_ws, 0, 512, stream);
  pad_sumabs_kernel<<<RED_BLOCKS + PAD_BLOCKS, 256, 0, stream>>>(x, xpad, W, scal);
  quant_kernel<<<RED_BLOCKS, 256, 0, stream>>>(W, WqT, scal);
  conv_kernel<<<1568, 256, 0, stream>>>(xpad, WqT, scal, b, out);
}